// Round 2
// baseline (858.594 us; speedup 1.0000x reference)
//
#include <hip/hip_runtime.h>
#include <math.h>

// ---------------- problem constants ----------------
#define NSP   14400      // H*W
#define CCH   512        // C
#define CKC   64         // CK
#define BSZ   8
#define OUTC  512

typedef unsigned short u16;
typedef unsigned int   u32;
typedef __attribute__((ext_vector_type(8))) short bf16x8;
typedef __attribute__((ext_vector_type(4))) float f32x4;

__device__ __forceinline__ u16 f2b(float f) {
    u32 u = __float_as_uint(f);
    return (u16)((u + 0x7fffu + ((u >> 16) & 1u)) >> 16);   // RNE
}
__device__ __forceinline__ float b2f(u16 h) {
    return __uint_as_float(((u32)h) << 16);
}

// ---------------- kernel: prep weights (bf16 concat [Wq;Wk], Wo, bias concat) ---
__global__ __launch_bounds__(256) void prep_w(
    const float* __restrict__ Wq, const float* __restrict__ Wk,
    const float* __restrict__ Wo, const float* __restrict__ bq,
    const float* __restrict__ bk,
    u16* __restrict__ wqk, u16* __restrict__ wo_bf, float* __restrict__ bqk)
{
    int idx = blockIdx.x * 256 + threadIdx.x;
    if (idx < 128 * 512) {
        int r = idx >> 9, c = idx & 511;
        float v = (r < 64) ? Wq[r * 512 + c] : Wk[(r - 64) * 512 + c];
        wqk[idx] = f2b(v);
    } else if (idx < 128 * 512 + 512 * 512) {
        int i = idx - 128 * 512;
        wo_bf[i] = f2b(Wo[i]);
    } else if (idx < 128 * 512 + 512 * 512 + 128) {
        int i = idx - (128 * 512 + 512 * 512);
        bqk[i] = (i < 64) ? bq[i] : bk[i - 64];
    }
}

// ---------------- kernel: Wov = Wo @ Wv  (fp32, 512^3, tiny) ----------------
__global__ __launch_bounds__(256) void wov_gemm(
    const float* __restrict__ A, const float* __restrict__ B, float* __restrict__ Cg)
{
    const int t = threadIdx.x;
    const int n0 = blockIdx.x * 64, m0 = blockIdx.y * 64;
    __shared__ float As[16][68], Bs[16][68];
    const int ti = t >> 4, tj = t & 15;
    const int a_kk = t & 15, a_mm = t >> 4;
    const int b_nn = t & 63, b_kk = t >> 6;
    float acc[4][4] = {};
    for (int k0 = 0; k0 < 512; k0 += 16) {
        #pragma unroll
        for (int r = 0; r < 4; ++r)
            As[a_kk][a_mm + r * 16] = A[(size_t)(m0 + a_mm + r * 16) * 512 + k0 + a_kk];
        #pragma unroll
        for (int r = 0; r < 4; ++r)
            Bs[b_kk + r * 4][b_nn] = B[(size_t)(k0 + b_kk + r * 4) * 512 + n0 + b_nn];
        __syncthreads();
        #pragma unroll
        for (int kk = 0; kk < 16; ++kk) {
            const float4 a4 = *(const float4*)&As[kk][ti * 4];
            const float4 b4 = *(const float4*)&Bs[kk][tj * 4];
            const float av[4] = {a4.x, a4.y, a4.z, a4.w};
            const float bv[4] = {b4.x, b4.y, b4.z, b4.w};
            #pragma unroll
            for (int i = 0; i < 4; ++i)
                #pragma unroll
                for (int j = 0; j < 4; ++j)
                    acc[i][j] = fmaf(av[i], bv[j], acc[i][j]);
        }
        __syncthreads();
    }
    #pragma unroll
    for (int i = 0; i < 4; ++i) {
        float4 o = {acc[i][0], acc[i][1], acc[i][2], acc[i][3]};
        *(float4*)&Cg[(size_t)(m0 + ti * 4 + i) * 512 + n0 + tj * 4] = o;
    }
}

// ---------------- kernel: bov = Wo @ bv ----------------
__global__ __launch_bounds__(64) void bov_kernel(
    const float* __restrict__ Wo, const float* __restrict__ bv, float* __restrict__ bov)
{
    int o = blockIdx.x * 64 + threadIdx.x;
    float s = 0.f;
    for (int c = 0; c < 512; ++c) s += Wo[(size_t)o * 512 + c] * bv[c];
    bov[o] = s;
}

// ---------------- kernel: x [b][c][n] f32 -> xT [b][n][c] bf16 ----------------
__global__ __launch_bounds__(256) void xpose_cvt(
    const float* __restrict__ x, u16* __restrict__ xT)
{
    const int b = blockIdx.z, c0 = blockIdx.y * 64, n0 = blockIdx.x * 64;
    const int t = threadIdx.x, w = t >> 6;
    __shared__ float T[64][65];
    const float* xp = x + ((size_t)b * CCH + c0) * NSP + n0;
    const int nn = t & 63;
    #pragma unroll
    for (int r = 0; r < 16; ++r) {
        int cc = r * 4 + w;
        T[cc][nn] = xp[(size_t)cc * NSP + nn];
    }
    __syncthreads();
    u16* op = xT + ((size_t)b * NSP + n0) * CCH + c0;
    const int cw = t & 63;
    #pragma unroll
    for (int r = 0; r < 16; ++r) {
        int nr = r * 4 + w;
        op[(size_t)nr * CCH + cw] = f2b(T[cw][nr]);
    }
}

// ---------------- kernel: bf16 MFMA GEMM ----------------
// C[b][m][n] = sum_k A[m][k] * B[b][n][k]   (B pre-transposed, k-contiguous)
// Block tile 128(m) x 96(n), BK=64, 4 waves (2x2), wave tile 64x48.
// MODE 0: f32 out + bias[m];  MODE 1: bf16 out + bias[m];  MODE 2: f32 out + Ybf16[b][m][n]
template<int MODE>
__global__ __launch_bounds__(256) void gemm_mfma(
    const u16* __restrict__ A, int lda, long aBatch,
    const u16* __restrict__ Bm, int K, long bBatch,
    float* __restrict__ outF, u16* __restrict__ outH, long cBatch,
    const float* __restrict__ bias, const u16* __restrict__ Ybf, long yBatch)
{
    const int t = threadIdx.x, lane = t & 63, w = t >> 6;
    const int b  = blockIdx.z;
    const int m0 = blockIdx.x * 128;
    const int n0 = blockIdx.y * 96;
    const int wm = w >> 1, wn = w & 1;

    __shared__ __align__(16) u16 As[128 * 64];   // [m][kk] XOR-swizzled, 16 KB
    __shared__ __align__(16) u16 Bs[96 * 64];    // [n][kk] XOR-swizzled, 12 KB

    const u16* Ap = A + (size_t)b * aBatch;
    const u16* Bp = Bm + (size_t)b * bBatch;

    const int srow = lane >> 3;          // 0..7 (row within 8-row chunk)
    const int kus  = (lane & 7) * 8;     // ushort k-offset 0..56 (16B granules)

    f32x4 acc[4][3];
    #pragma unroll
    for (int i = 0; i < 4; ++i)
        #pragma unroll
        for (int j = 0; j < 3; ++j)
            acc[i][j] = (f32x4){0.f, 0.f, 0.f, 0.f};

    for (int k0 = 0; k0 < K; k0 += 64) {
        // ---- reg-stage global (coalesced: 8 lanes cover one 128B row) ----
        bf16x8 ar[4], br[3];
        #pragma unroll
        for (int i = 0; i < 4; ++i) {
            int row = (w * 4 + i) * 8 + srow;           // 0..127
            ar[i] = *(const bf16x8*)(Ap + (size_t)(m0 + row) * lda + k0 + kus);
        }
        #pragma unroll
        for (int i = 0; i < 3; ++i) {
            int row = (w * 3 + i) * 8 + srow;           // 0..95
            br[i] = *(const bf16x8*)(Bp + (size_t)(n0 + row) * K + k0 + kus);
        }
        __syncthreads();   // previous iter's ds_reads done before overwrite
        // ---- LDS write, XOR-swizzled (T2): slot k ^= (row&7)<<3 ushorts ----
        #pragma unroll
        for (int i = 0; i < 4; ++i) {
            int row = (w * 4 + i) * 8 + srow;
            *(bf16x8*)&As[row * 64 + (kus ^ ((row & 7) << 3))] = ar[i];
        }
        #pragma unroll
        for (int i = 0; i < 3; ++i) {
            int row = (w * 3 + i) * 8 + srow;
            *(bf16x8*)&Bs[row * 64 + (kus ^ ((row & 7) << 3))] = br[i];
        }
        __syncthreads();
        // ---- fragments + MFMA (k-mapping identical for A and B => correct) ----
        #pragma unroll
        for (int kk = 0; kk < 2; ++kk) {
            const int kf = kk * 32 + (lane >> 4) * 8;
            bf16x8 af[4], bg[3];
            #pragma unroll
            for (int fm = 0; fm < 4; ++fm) {
                int ml = wm * 64 + fm * 16 + (lane & 15);
                af[fm] = *(const bf16x8*)&As[ml * 64 + (kf ^ ((ml & 7) << 3))];
            }
            #pragma unroll
            for (int fn = 0; fn < 3; ++fn) {
                int nl = wn * 48 + fn * 16 + (lane & 15);
                bg[fn] = *(const bf16x8*)&Bs[nl * 64 + (kf ^ ((nl & 7) << 3))];
            }
            #pragma unroll
            for (int fm = 0; fm < 4; ++fm)
                #pragma unroll
                for (int fn = 0; fn < 3; ++fn)
                    acc[fm][fn] = __builtin_amdgcn_mfma_f32_16x16x32_bf16(
                        af[fm], bg[fn], acc[fm][fn], 0, 0, 0);
        }
    }

    // ---- epilogue: C/D layout col=lane&15, row=(lane>>4)*4+reg (verified) ----
    const int rbase = (lane >> 4) * 4;
    const int cloc  = lane & 15;
    #pragma unroll
    for (int fm = 0; fm < 4; ++fm) {
        #pragma unroll
        for (int fn = 0; fn < 3; ++fn) {
            const int gm0 = m0 + wm * 64 + fm * 16 + rbase;
            const int gn  = n0 + wn * 48 + fn * 16 + cloc;
            #pragma unroll
            for (int r = 0; r < 4; ++r) {
                const int gm = gm0 + r;
                const float v = acc[fm][fn][r];
                const size_t idx = (size_t)b * cBatch + (size_t)gm * NSP + gn;
                if (MODE == 0)      outF[idx] = v + bias[gm];
                else if (MODE == 1) outH[idx] = f2b(v + bias[gm]);
                else                outF[idx] = v + b2f(Ybf[(size_t)b * yBatch + (size_t)gm * NSP + gn]);
            }
        }
    }
}

// ---------------- kernel: k softmax stats (max, 1/sum exp) over N ----------------
__global__ __launch_bounds__(256) void k_stats(
    const float* __restrict__ Oqk, float* __restrict__ kmax, float* __restrict__ kinv)
{
    const int row = blockIdx.x;             // b*64+k
    const int b = row >> 6, k = row & 63;
    const float4* p4 = (const float4*)(Oqk + ((size_t)b * 128 + 64 + k) * NSP);
    const int t = threadIdx.x;

    float m = -1e30f;
    for (int i = t; i < NSP / 4; i += 256) {
        float4 v = p4[i];
        m = fmaxf(m, fmaxf(fmaxf(v.x, v.y), fmaxf(v.z, v.w)));
    }
    for (int o = 32; o; o >>= 1) m = fmaxf(m, __shfl_xor(m, o));
    __shared__ float redm[4];
    const int wid = t >> 6, lane = t & 63;
    if (lane == 0) redm[wid] = m;
    __syncthreads();
    m = fmaxf(fmaxf(redm[0], redm[1]), fmaxf(redm[2], redm[3]));

    float s = 0.f;
    for (int i = t; i < NSP / 4; i += 256) {
        float4 v = p4[i];
        s += __expf(v.x - m) + __expf(v.y - m) + __expf(v.z - m) + __expf(v.w - m);
    }
    for (int o = 32; o; o >>= 1) s += __shfl_xor(s, o);
    __shared__ float reds[4];
    if (lane == 0) reds[wid] = s;
    __syncthreads();
    s = reds[0] + reds[1] + reds[2] + reds[3];
    if (t == 0) { kmax[row] = m; kinv[row] = 1.0f / s; }
}

// ---------------- kernel: q softmax over CK=64 -> qT bf16 [b][n][64] ----------------
__global__ __launch_bounds__(256) void q_softmax(
    const float* __restrict__ Oqk, u16* __restrict__ qT)
{
    const long idx = (long)blockIdx.x * 256 + threadIdx.x;  // < B*N = 115200
    const int b = (int)(idx / NSP);
    const int n = (int)(idx % NSP);
    const float* base = Oqk + (size_t)b * 128 * NSP + n;
    float q[64];
    float m = -1e30f;
    #pragma unroll
    for (int k = 0; k < 64; ++k) { q[k] = base[(size_t)k * NSP]; m = fmaxf(m, q[k]); }
    float s = 0.f;
    #pragma unroll
    for (int k = 0; k < 64; ++k) { q[k] = __expf(q[k] - m); s += q[k]; }
    const float inv = 1.0f / s;
    u32 pk[32];
    #pragma unroll
    for (int i = 0; i < 32; ++i) {
        pk[i] = (u32)f2b(q[2 * i] * inv) | ((u32)f2b(q[2 * i + 1] * inv) << 16);
    }
    uint4* dst = (uint4*)(qT + ((size_t)b * NSP + n) * 64);
    const uint4* src = (const uint4*)pk;
    #pragma unroll
    for (int i = 0; i < 8; ++i) dst[i] = src[i];
}

// ---------------- kernel: KX partials (split over n): KX[b][k][c] = sum ksm*x ---
__global__ __launch_bounds__(256) void kx_partial(
    const float* __restrict__ Oqk, const float* __restrict__ x,
    const float* __restrict__ kmax, const float* __restrict__ kinv,
    float* __restrict__ part)
{
    const int c0 = blockIdx.x * 64;   // 8 c-tiles
    const int sp = blockIdx.y;        // 15 splits of 960
    const int b  = blockIdx.z;
    const int t  = threadIdx.x;
    const int ti = t >> 4, tj = t & 15;
    __shared__ float Ks[16][68];
    __shared__ float Vs[16][68];
    const int l_nn = t & 15, l_r0 = t >> 4;
    const float* kbase = Oqk + ((size_t)b * 128 + 64) * NSP;
    const float* xbase = x + (size_t)b * CCH * NSP;

    float km[4], ki[4];
    #pragma unroll
    for (int r = 0; r < 4; ++r) {
        int k = l_r0 + r * 16;
        km[r] = kmax[b * 64 + k];
        ki[r] = kinv[b * 64 + k];
    }
    float acc[4][4] = {};
    const int ns = sp * 960;
    for (int n0 = ns; n0 < ns + 960; n0 += 16) {
        #pragma unroll
        for (int r = 0; r < 4; ++r) {
            int kc = l_r0 + r * 16;
            Ks[l_nn][kc] = __expf(kbase[(size_t)kc * NSP + n0 + l_nn] - km[r]) * ki[r];
            Vs[l_nn][kc] = xbase[(size_t)(c0 + kc) * NSP + n0 + l_nn];
        }
        __syncthreads();
        #pragma unroll
        for (int nn = 0; nn < 16; ++nn) {
            const float4 a4 = *(const float4*)&Ks[nn][ti * 4];
            const float4 b4 = *(const float4*)&Vs[nn][tj * 4];
            const float av[4] = {a4.x, a4.y, a4.z, a4.w};
            const float bv[4] = {b4.x, b4.y, b4.z, b4.w};
            #pragma unroll
            for (int i = 0; i < 4; ++i)
                #pragma unroll
                for (int j = 0; j < 4; ++j)
                    acc[i][j] = fmaf(av[i], bv[j], acc[i][j]);
        }
        __syncthreads();
    }
    #pragma unroll
    for (int i = 0; i < 4; ++i) {
        float4 o = {acc[i][0], acc[i][1], acc[i][2], acc[i][3]};
        *(float4*)&part[(size_t)sp * (BSZ * 64 * 512) +
                        ((size_t)b * 64 + ti * 4 + i) * 512 + c0 + tj * 4] = o;
    }
}

// ---------------- kernel: reduce KX partials ----------------
__global__ __launch_bounds__(256) void kx_reduce(
    const float* __restrict__ part, float* __restrict__ KXf)
{
    const size_t idx = (size_t)blockIdx.x * 256 + threadIdx.x;  // < 262144
    float s = 0.f;
    #pragma unroll
    for (int sp = 0; sp < 15; ++sp) s += part[(size_t)sp * 262144 + idx];
    KXf[idx] = s;
}

// ---------------- kernel: Wco[o][bk] = gamma*(Wov @ KX^T + bov) -> bf16 ----------
__global__ __launch_bounds__(256) void wco_gemm(
    const float* __restrict__ Wov, const float* __restrict__ KXf,
    const float* __restrict__ bov, const float* __restrict__ gamma,
    u16* __restrict__ Wco)
{
    const int t = threadIdx.x;
    const int n0 = blockIdx.x * 64, m0 = blockIdx.y * 64;
    __shared__ float As[16][68], Bs[16][68];
    const int ti = t >> 4, tj = t & 15;
    const int a_kk = t & 15, a_mm = t >> 4;
    const int s_nn = t & 63, s_kq = t >> 6;
    float acc[4][4] = {};
    for (int k0 = 0; k0 < 512; k0 += 16) {
        #pragma unroll
        for (int r = 0; r < 4; ++r)
            As[a_kk][a_mm + r * 16] = Wov[(size_t)(m0 + a_mm + r * 16) * 512 + k0 + a_kk];
        {   // B transposed stage: Bs[kk][nn] = KXf[n0+nn][k0+kk]
            const float4 v = *(const float4*)&KXf[(size_t)(n0 + s_nn) * 512 + k0 + s_kq * 4];
            Bs[s_kq * 4 + 0][s_nn] = v.x;
            Bs[s_kq * 4 + 1][s_nn] = v.y;
            Bs[s_kq * 4 + 2][s_nn] = v.z;
            Bs[s_kq * 4 + 3][s_nn] = v.w;
        }
        __syncthreads();
        #pragma unroll
        for (int kk = 0; kk < 16; ++kk) {
            const float4 a4 = *(const float4*)&As[kk][ti * 4];
            const float4 b4 = *(const float4*)&Bs[kk][tj * 4];
            const float av[4] = {a4.x, a4.y, a4.z, a4.w};
            const float bv[4] = {b4.x, b4.y, b4.z, b4.w};
            #pragma unroll
            for (int i = 0; i < 4; ++i)
                #pragma unroll
                for (int j = 0; j < 4; ++j)
                    acc[i][j] = fmaf(av[i], bv[j], acc[i][j]);
        }
        __syncthreads();
    }
    const float g = gamma[0];
    #pragma unroll
    for (int i = 0; i < 4; ++i) {
        const int m = m0 + ti * 4 + i;
        const float bb = bov[m];
        #pragma unroll
        for (int j = 0; j < 4; ++j)
            Wco[(size_t)m * 512 + n0 + tj * 4 + j] = f2b(g * (acc[i][j] + bb));
    }
}

// ---------------- launcher ----------------
extern "C" void kernel_launch(void* const* d_in, const int* in_sizes, int n_in,
                              void* d_out, int out_size, void* d_ws, size_t ws_size,
                              hipStream_t stream)
{
    const float* x     = (const float*)d_in[0];
    const float* Wq    = (const float*)d_in[1];
    const float* bq    = (const float*)d_in[2];
    const float* Wk    = (const float*)d_in[3];
    const float* bk    = (const float*)d_in[4];
    const float* Wv    = (const float*)d_in[5];
    const float* bv    = (const float*)d_in[6];
    const float* gamma = (const float*)d_in[7];
    const float* Wo    = (const float*)d_in[8];
    const float* bo    = (const float*)d_in[9];
    float* out = (float*)d_out;

    // ---- workspace carve (bytes, 256-aligned) ----
    char* base = (char*)d_ws;
    size_t off = 0;
    auto carve = [&](size_t bytes) { char* p = base + off; off = (off + bytes + 255) & ~(size_t)255; return p; };
    u16*   wqk   = (u16*)  carve(128 * 512 * 2);
    u16*   wo_bf = (u16*)  carve(512 * 512 * 2);
    float* bqk   = (float*)carve(128 * 4);
    float* Wov   = (float*)carve(512 * 512 * 4);
    float* bovp  = (float*)carve(512 * 4);
    u16*   xT    = (u16*)  carve((size_t)BSZ * NSP * CCH * 2);      // 118 MB
    float* Oqk   = (float*)carve((size_t)BSZ * 128 * NSP * 4);      //  59 MB
    u16*   Ybf   = (u16*)  carve((size_t)BSZ * 512 * NSP * 2);      // 118 MB
    float* kmax  = (float*)carve(512 * 4);
    float* kinv  = (float*)carve(512 * 4);
    u16*   qT    = (u16*)  carve((size_t)BSZ * NSP * 64 * 2);       //  15 MB
    float* part  = (float*)carve((size_t)15 * BSZ * 64 * 512 * 4);  //  16 MB
    float* KXf   = (float*)carve((size_t)BSZ * 64 * 512 * 4);       //   1 MB
    u16*   Wco   = (u16*)  carve(512 * 512 * 2);

    // 1. weight prep (bf16 casts + bias concat)
    prep_w<<<dim3((128 * 512 + 512 * 512 + 128 + 255) / 256), dim3(256), 0, stream>>>(
        Wq, Wk, Wo, bq, bk, wqk, wo_bf, bqk);
    // 2. Wov = Wo @ Wv ; bov = Wo @ bv
    wov_gemm<<<dim3(8, 8), dim3(256), 0, stream>>>(Wo, Wv, Wov);
    bov_kernel<<<dim3(8), dim3(64), 0, stream>>>(Wo, bv, bovp);
    // 3. x -> xT bf16
    xpose_cvt<<<dim3(NSP / 64, CCH / 64, BSZ), dim3(256), 0, stream>>>(x, xT);
    // 4. q,k linear:  Oqk[b][0..128) = [Wq;Wk] @ x + bqk   (f32 out)
    gemm_mfma<0><<<dim3(1, NSP / 96, BSZ), dim3(256), 0, stream>>>(
        wqk, 512, 0L, xT, 512, (long)NSP * 512,
        Oqk, (u16*)nullptr, (long)128 * NSP, bqk, (const u16*)nullptr, 0L);
    // 5. Y = Wo @ x + bo  (bf16 out)
    gemm_mfma<1><<<dim3(4, NSP / 96, BSZ), dim3(256), 0, stream>>>(
        wo_bf, 512, 0L, xT, 512, (long)NSP * 512,
        (float*)nullptr, Ybf, (long)512 * NSP, bo, (const u16*)nullptr, 0L);
    // 6. k softmax stats
    k_stats<<<dim3(BSZ * 64), dim3(256), 0, stream>>>(Oqk, kmax, kinv);
    // 7. q softmax -> qT bf16
    q_softmax<<<dim3(BSZ * NSP / 256), dim3(256), 0, stream>>>(Oqk, qT);
    // 8. KX partials + reduce
    kx_partial<<<dim3(CCH / 64, 15, BSZ), dim3(256), 0, stream>>>(Oqk, x, kmax, kinv, part);
    kx_reduce<<<dim3(262144 / 256), dim3(256), 0, stream>>>(part, KXf);
    // 9. Wco = gamma*(Wov @ KX^T + bov)  bf16 [o][b*64+k]
    wco_gemm<<<dim3(8, 8), dim3(256), 0, stream>>>(Wov, KXf, bovp, gamma, Wco);
    // 10. out = Wco_b @ qT_b^T + Y   (K=64)
    gemm_mfma<2><<<dim3(4, NSP / 96, BSZ), dim3(256), 0, stream>>>(
        Wco, 512, 64L, qT, 64, (long)NSP * 64,
        out, (u16*)nullptr, (long)512 * NSP, (const float*)nullptr, Ybf, (long)512 * NSP);
}

// Round 5
// 705.427 us; speedup vs baseline: 1.2171x; 1.2171x over previous
//
#include <hip/hip_runtime.h>
#include <math.h>

// ---------------- problem constants ----------------
#define NSP   14400      // H*W
#define CCH   512        // C
#define BSZ   8

typedef unsigned short u16;
typedef unsigned int   u32;
typedef __attribute__((ext_vector_type(8))) short bf16x8;
typedef __attribute__((ext_vector_type(4))) float f32x4;

__device__ __forceinline__ u16 f2b(float f) {
    u32 u = __float_as_uint(f);
    return (u16)((u + 0x7fffu + ((u >> 16) & 1u)) >> 16);   // RNE
}

// ---------------- kernel: prep weights ----------------
__global__ __launch_bounds__(256) void prep_w(
    const float* __restrict__ Wq, const float* __restrict__ Wk,
    const float* __restrict__ Wo, const float* __restrict__ bq,
    const float* __restrict__ bk,
    u16* __restrict__ wqk, u16* __restrict__ wo_bf, float* __restrict__ bqk)
{
    int idx = blockIdx.x * 256 + threadIdx.x;
    if (idx < 128 * 512) {
        int r = idx >> 9, c = idx & 511;
        float v = (r < 64) ? Wq[r * 512 + c] : Wk[(r - 64) * 512 + c];
        wqk[idx] = f2b(v);
    } else if (idx < 128 * 512 + 512 * 512) {
        int i = idx - 128 * 512;
        wo_bf[i] = f2b(Wo[i]);
    } else if (idx < 128 * 512 + 512 * 512 + 128) {
        int i = idx - (128 * 512 + 512 * 512);
        bqk[i] = (i < 64) ? bq[i] : bk[i - 64];
    }
}

// ---------------- kernel: Wov = Wo @ Wv (fp32, tiny) ----------------
__global__ __launch_bounds__(256) void wov_gemm(
    const float* __restrict__ A, const float* __restrict__ B, float* __restrict__ Cg)
{
    const int t = threadIdx.x;
    const int n0 = blockIdx.x * 64, m0 = blockIdx.y * 64;
    __shared__ float As[16][68], Bs[16][68];
    const int ti = t >> 4, tj = t & 15;
    const int a_kk = t & 15, a_mm = t >> 4;
    const int b_nn = t & 63, b_kk = t >> 6;
    float acc[4][4] = {};
    for (int k0 = 0; k0 < 512; k0 += 16) {
        #pragma unroll
        for (int r = 0; r < 4; ++r)
            As[a_kk][a_mm + r * 16] = A[(size_t)(m0 + a_mm + r * 16) * 512 + k0 + a_kk];
        #pragma unroll
        for (int r = 0; r < 4; ++r)
            Bs[b_kk + r * 4][b_nn] = B[(size_t)(k0 + b_kk + r * 4) * 512 + n0 + b_nn];
        __syncthreads();
        #pragma unroll
        for (int kk = 0; kk < 16; ++kk) {
            const float4 a4 = *(const float4*)&As[kk][ti * 4];
            const float4 b4 = *(const float4*)&Bs[kk][tj * 4];
            const float av[4] = {a4.x, a4.y, a4.z, a4.w};
            const float bv[4] = {b4.x, b4.y, b4.z, b4.w};
            #pragma unroll
            for (int i = 0; i < 4; ++i)
                #pragma unroll
                for (int j = 0; j < 4; ++j)
                    acc[i][j] = fmaf(av[i], bv[j], acc[i][j]);
        }
        __syncthreads();
    }
    #pragma unroll
    for (int i = 0; i < 4; ++i) {
        float4 o = {acc[i][0], acc[i][1], acc[i][2], acc[i][3]};
        *(float4*)&Cg[(size_t)(m0 + ti * 4 + i) * 512 + n0 + tj * 4] = o;
    }
}

// ---------------- kernel: bov = Wo @ bv ----------------
__global__ __launch_bounds__(64) void bov_kernel(
    const float* __restrict__ Wo, const float* __restrict__ bv, float* __restrict__ bov)
{
    int o = blockIdx.x * 64 + threadIdx.x;
    float s = 0.f;
    for (int c = 0; c < 512; ++c) s += Wo[(size_t)o * 512 + c] * bv[c];
    bov[o] = s;
}

// ---------------- kernel: x f32 [b][c][n] -> xT bf16 [b][n][c] AND xbf bf16 [b][c][n] --
__global__ __launch_bounds__(256) void xpose_cvt(
    const float* __restrict__ x, u16* __restrict__ xT, u16* __restrict__ xbf)
{
    const int b = blockIdx.z, c0 = blockIdx.y * 64, n0 = blockIdx.x * 64;
    const int t = threadIdx.x, w = t >> 6;
    __shared__ float T[64][65];
    const float* xp = x + ((size_t)b * CCH + c0) * NSP + n0;
    u16* op2 = xbf + ((size_t)b * CCH + c0) * NSP + n0;
    const int nn = t & 63;
    #pragma unroll
    for (int r = 0; r < 16; ++r) {
        int cc = r * 4 + w;
        float v = xp[(size_t)cc * NSP + nn];
        T[cc][nn] = v;
        op2[(size_t)cc * NSP + nn] = f2b(v);
    }
    __syncthreads();
    u16* op = xT + ((size_t)b * NSP + n0) * CCH + c0;
    const int cw = t & 63;
    #pragma unroll
    for (int r = 0; r < 16; ++r) {
        int nr = r * 4 + w;
        op[(size_t)nr * CCH + cw] = f2b(T[cw][nr]);
    }
}

// ---------------- kernel: qk GEMM + fused q-softmax epilogue ----------------
// acc[m][n] = sum_c wqk[m][c]*x[c][n] + bqk[m];  m<64: q (softmax over m -> qT bf16)
//                                                m>=64: k (f32 -> Okk)
__global__ __launch_bounds__(256) void qk_gemm(
    const u16* __restrict__ wqk, const u16* __restrict__ xT,
    const float* __restrict__ bqk,
    float* __restrict__ Okk, u16* __restrict__ qT)
{
    const int t = threadIdx.x, lane = t & 63, w = t >> 6;
    const int b  = blockIdx.z;
    const int n0 = blockIdx.x * 96;
    const int wm = w >> 1, wn = w & 1;

    __shared__ __align__(16) u16 As[128 * 64];
    __shared__ __align__(16) u16 Bs[96 * 64];

    const u16* Bp = xT + (size_t)b * NSP * 512;
    const int srow = lane >> 3;
    const int kus  = (lane & 7) * 8;

    f32x4 acc[4][3];
    #pragma unroll
    for (int i = 0; i < 4; ++i)
        #pragma unroll
        for (int j = 0; j < 3; ++j)
            acc[i][j] = (f32x4){0.f, 0.f, 0.f, 0.f};

    for (int k0 = 0; k0 < 512; k0 += 64) {
        bf16x8 ar[4], br[3];
        #pragma unroll
        for (int i = 0; i < 4; ++i) {
            int row = (w * 4 + i) * 8 + srow;
            ar[i] = *(const bf16x8*)(wqk + (size_t)row * 512 + k0 + kus);
        }
        #pragma unroll
        for (int i = 0; i < 3; ++i) {
            int row = (w * 3 + i) * 8 + srow;
            br[i] = *(const bf16x8*)(Bp + (size_t)(n0 + row) * 512 + k0 + kus);
        }
        __syncthreads();
        #pragma unroll
        for (int i = 0; i < 4; ++i) {
            int row = (w * 4 + i) * 8 + srow;
            *(bf16x8*)&As[row * 64 + (kus ^ ((row & 7) << 3))] = ar[i];
        }
        #pragma unroll
        for (int i = 0; i < 3; ++i) {
            int row = (w * 3 + i) * 8 + srow;
            *(bf16x8*)&Bs[row * 64 + (kus ^ ((row & 7) << 3))] = br[i];
        }
        __syncthreads();
        #pragma unroll
        for (int kk = 0; kk < 2; ++kk) {
            const int kf = kk * 32 + (lane >> 4) * 8;
            bf16x8 af[4], bg[3];
            #pragma unroll
            for (int fm = 0; fm < 4; ++fm) {
                int ml = wm * 64 + fm * 16 + (lane & 15);
                af[fm] = *(const bf16x8*)&As[ml * 64 + (kf ^ ((ml & 7) << 3))];
            }
            #pragma unroll
            for (int fn = 0; fn < 3; ++fn) {
                int nl = wn * 48 + fn * 16 + (lane & 15);
                bg[fn] = *(const bf16x8*)&Bs[nl * 64 + (kf ^ ((nl & 7) << 3))];
            }
            #pragma unroll
            for (int fm = 0; fm < 4; ++fm)
                #pragma unroll
                for (int fn = 0; fn < 3; ++fn)
                    acc[fm][fn] = __builtin_amdgcn_mfma_f32_16x16x32_bf16(
                        af[fm], bg[fn], acc[fm][fn], 0, 0, 0);
        }
    }

    const int rbase = (lane >> 4) * 4;
    const int cloc  = lane & 15;
    if (wm == 0) {
        // q rows 0..63: channel softmax per column, write qT[b][n][64] bf16
        #pragma unroll
        for (int fn = 0; fn < 3; ++fn) {
            const int gn = n0 + wn * 48 + fn * 16 + cloc;
            float v[4][4];
            float mx = -1e30f;
            #pragma unroll
            for (int fm = 0; fm < 4; ++fm)
                #pragma unroll
                for (int r = 0; r < 4; ++r) {
                    v[fm][r] = acc[fm][fn][r] + bqk[fm * 16 + rbase + r];
                    mx = fmaxf(mx, v[fm][r]);
                }
            mx = fmaxf(mx, __shfl_xor(mx, 16));
            mx = fmaxf(mx, __shfl_xor(mx, 32));
            float s = 0.f;
            #pragma unroll
            for (int fm = 0; fm < 4; ++fm)
                #pragma unroll
                for (int r = 0; r < 4; ++r) {
                    v[fm][r] = __expf(v[fm][r] - mx);
                    s += v[fm][r];
                }
            s += __shfl_xor(s, 16);
            s += __shfl_xor(s, 32);
            const float inv = 1.0f / s;
            u16* qrow = qT + ((size_t)b * NSP + gn) * 64;
            #pragma unroll
            for (int fm = 0; fm < 4; ++fm) {
                ushort4 pk;
                pk.x = f2b(v[fm][0] * inv);
                pk.y = f2b(v[fm][1] * inv);
                pk.z = f2b(v[fm][2] * inv);
                pk.w = f2b(v[fm][3] * inv);
                *(ushort4*)&qrow[fm * 16 + rbase] = pk;
            }
        }
    } else {
        // k rows: f32 linear (bias added) -> Okk[b][64][N]
        #pragma unroll
        for (int fm = 0; fm < 4; ++fm) {
            #pragma unroll
            for (int fn = 0; fn < 3; ++fn) {
                const int gn = n0 + wn * 48 + fn * 16 + cloc;
                #pragma unroll
                for (int r = 0; r < 4; ++r) {
                    const int gmk = fm * 16 + rbase + r;
                    Okk[((size_t)b * 64 + gmk) * NSP + gn] = acc[fm][fn][r] + bqk[64 + gmk];
                }
            }
        }
    }
}

// ---------------- kernel: k softmax stats over N ----------------
__global__ __launch_bounds__(256) void k_stats(
    const float* __restrict__ Okk, float* __restrict__ kmax, float* __restrict__ kinv)
{
    const int row = blockIdx.x;             // b*64+k
    const float4* p4 = (const float4*)(Okk + (size_t)row * NSP);
    const int t = threadIdx.x;

    float m = -1e30f;
    for (int i = t; i < NSP / 4; i += 256) {
        float4 v = p4[i];
        m = fmaxf(m, fmaxf(fmaxf(v.x, v.y), fmaxf(v.z, v.w)));
    }
    for (int o = 32; o; o >>= 1) m = fmaxf(m, __shfl_xor(m, o));
    __shared__ float redm[4];
    const int wid = t >> 6, lane = t & 63;
    if (lane == 0) redm[wid] = m;
    __syncthreads();
    m = fmaxf(fmaxf(redm[0], redm[1]), fmaxf(redm[2], redm[3]));

    float s = 0.f;
    for (int i = t; i < NSP / 4; i += 256) {
        float4 v = p4[i];
        s += __expf(v.x - m) + __expf(v.y - m) + __expf(v.z - m) + __expf(v.w - m);
    }
    for (int o = 32; o; o >>= 1) s += __shfl_xor(s, o);
    __shared__ float reds[4];
    if (lane == 0) reds[wid] = s;
    __syncthreads();
    s = reds[0] + reds[1] + reds[2] + reds[3];
    if (t == 0) { kmax[row] = m; kinv[row] = 1.0f / s; }
}

// ---------------- kernel: KX partials via MFMA ----------------
// part[sp][b][k][c] = sum_{n in chunk} ksm_bf16[k,n] * xbf[c,n]
// M=64(k) x N=128(c) tile, contraction chunk 576 (9 x BK=64). 4 waves, each 64x32.
__global__ __launch_bounds__(256) void kx_mfma(
    const float* __restrict__ Okk, const u16* __restrict__ xbf,
    const float* __restrict__ kmax, const float* __restrict__ kinv,
    float* __restrict__ part)
{
    const int bid = blockIdx.x;                  // 800 blocks
    const int swz = (bid & 7) * 100 + (bid >> 3);   // T1 chunked (800%8==0)
    const int c_t = swz & 3;
    const int tmp = swz >> 2;
    const int sp  = tmp % 25;
    const int b   = tmp / 25;
    const int c0  = c_t * 128;
    const int t = threadIdx.x, lane = t & 63, w = t >> 6;

    __shared__ __align__(16) u16 As[64 * 64];    // ksm bf16, swizzled
    __shared__ __align__(16) u16 Bs[128 * 64];   // x bf16, swizzled
    __shared__ float kms[64], kis[64];
    if (t < 64) { kms[t] = kmax[b * 64 + t]; kis[t] = kinv[b * 64 + t]; }
    __syncthreads();

    const float* kb = Okk + (size_t)b * 64 * NSP;
    const u16*   xb = xbf + ((size_t)b * CCH + c0) * NSP;

    const int arow = t >> 4;            // 0..15 (+p*16)
    const int acol = (t & 15) * 4;      // f32 quad / u16 quad
    const int brow = t >> 3;            // 0..31 (+p*32)
    const int bgr  = (t & 7) * 8;

    f32x4 acc[4][2];
    #pragma unroll
    for (int i = 0; i < 4; ++i)
        #pragma unroll
        for (int j = 0; j < 2; ++j)
            acc[i][j] = (f32x4){0.f, 0.f, 0.f, 0.f};

    const int ns = sp * 576;
    for (int nb = ns; nb < ns + 576; nb += 64) {
        float4 av[4];
        bf16x8 bv[4];
        #pragma unroll
        for (int p = 0; p < 4; ++p) {
            int row = arow + p * 16;
            av[p] = *(const float4*)&kb[(size_t)row * NSP + nb + acol];
        }
        #pragma unroll
        for (int p = 0; p < 4; ++p) {
            int row = brow + p * 32;
            bv[p] = *(const bf16x8*)&xb[(size_t)row * NSP + nb + bgr];
        }
        __syncthreads();
        #pragma unroll
        for (int p = 0; p < 4; ++p) {
            int row = arow + p * 16;
            float km = kms[row], ki = kis[row];
            ushort4 e;
            e.x = f2b(__expf(av[p].x - km) * ki);
            e.y = f2b(__expf(av[p].y - km) * ki);
            e.z = f2b(__expf(av[p].z - km) * ki);
            e.w = f2b(__expf(av[p].w - km) * ki);
            *(ushort4*)&As[row * 64 + (acol ^ ((row & 7) << 3))] = e;
        }
        #pragma unroll
        for (int p = 0; p < 4; ++p) {
            int row = brow + p * 32;
            *(bf16x8*)&Bs[row * 64 + (bgr ^ ((row & 7) << 3))] = bv[p];
        }
        __syncthreads();
        #pragma unroll
        for (int kk = 0; kk < 2; ++kk) {
            const int kf = kk * 32 + (lane >> 4) * 8;
            bf16x8 af[4], bg[2];
            #pragma unroll
            for (int fm = 0; fm < 4; ++fm) {
                int ml = fm * 16 + (lane & 15);
                af[fm] = *(const bf16x8*)&As[ml * 64 + (kf ^ ((ml & 7) << 3))];
            }
            #pragma unroll
            for (int fn = 0; fn < 2; ++fn) {
                int nl = w * 32 + fn * 16 + (lane & 15);
                bg[fn] = *(const bf16x8*)&Bs[nl * 64 + (kf ^ ((nl & 7) << 3))];
            }
            #pragma unroll
            for (int fm = 0; fm < 4; ++fm)
                #pragma unroll
                for (int fn = 0; fn < 2; ++fn)
                    acc[fm][fn] = __builtin_amdgcn_mfma_f32_16x16x32_bf16(
                        af[fm], bg[fn], acc[fm][fn], 0, 0, 0);
        }
    }

    const int rbase = (lane >> 4) * 4;
    const int cloc  = lane & 15;
    #pragma unroll
    for (int fm = 0; fm < 4; ++fm)
        #pragma unroll
        for (int fn = 0; fn < 2; ++fn)
            #pragma unroll
            for (int r = 0; r < 4; ++r) {
                const int k = fm * 16 + rbase + r;
                const int c = c0 + w * 32 + fn * 16 + cloc;
                part[(((size_t)sp * 8 + b) * 64 + k) * 512 + c] = acc[fm][fn][r];
            }
}

// ---------------- kernel: reduce KX partials ----------------
__global__ __launch_bounds__(256) void kx_reduce(
    const float* __restrict__ part, float* __restrict__ KXf)
{
    const size_t idx = (size_t)blockIdx.x * 256 + threadIdx.x;  // < 262144
    float s = 0.f;
    #pragma unroll
    for (int sp = 0; sp < 25; ++sp) s += part[(size_t)sp * 262144 + idx];
    KXf[idx] = s;
}

// ---------------- kernel: Wco[o][b*64+k] = gamma*(Wov @ KX^T + bov) bf16 --------
__global__ __launch_bounds__(256) void wco_gemm(
    const float* __restrict__ Wov, const float* __restrict__ KXf,
    const float* __restrict__ bov, const float* __restrict__ gamma,
    u16* __restrict__ Wco)
{
    const int t = threadIdx.x;
    const int n0 = blockIdx.x * 64, m0 = blockIdx.y * 64;
    __shared__ float As[16][68], Bs[16][68];
    const int ti = t >> 4, tj = t & 15;
    const int a_kk = t & 15, a_mm = t >> 4;
    const int s_nn = t & 63, s_kq = t >> 6;
    float acc[4][4] = {};
    for (int k0 = 0; k0 < 512; k0 += 16) {
        #pragma unroll
        for (int r = 0; r < 4; ++r)
            As[a_kk][a_mm + r * 16] = Wov[(size_t)(m0 + a_mm + r * 16) * 512 + k0 + a_kk];
        {
            const float4 v = *(const float4*)&KXf[(size_t)(n0 + s_nn) * 512 + k0 + s_kq * 4];
            Bs[s_kq * 4 + 0][s_nn] = v.x;
            Bs[s_kq * 4 + 1][s_nn] = v.y;
            Bs[s_kq * 4 + 2][s_nn] = v.z;
            Bs[s_kq * 4 + 3][s_nn] = v.w;
        }
        __syncthreads();
        #pragma unroll
        for (int kk = 0; kk < 16; ++kk) {
            const float4 a4 = *(const float4*)&As[kk][ti * 4];
            const float4 b4 = *(const float4*)&Bs[kk][tj * 4];
            const float av[4] = {a4.x, a4.y, a4.z, a4.w};
            const float bv[4] = {b4.x, b4.y, b4.z, b4.w};
            #pragma unroll
            for (int i = 0; i < 4; ++i)
                #pragma unroll
                for (int j = 0; j < 4; ++j)
                    acc[i][j] = fmaf(av[i], bv[j], acc[i][j]);
        }
        __syncthreads();
    }
    const float g = gamma[0];
    #pragma unroll
    for (int i = 0; i < 4; ++i) {
        const int m = m0 + ti * 4 + i;
        const float bb = bov[m];
        #pragma unroll
        for (int j = 0; j < 4; ++j)
            Wco[(size_t)m * 512 + n0 + tj * 4 + j] = f2b(g * (acc[i][j] + bb));
    }
}

// ---------------- kernel: fused output GEMM, K=576 = [qT(64) ; xT(512)] ----------
// out[b][m][n] = sum_{k<64} Wco[m][b*64+k]*qT[b][n][k]
//             + sum_{c} wo_bf[m][c]*xT[b][n][c] + bo[m]
__global__ __launch_bounds__(256) void fused_out(
    const u16* __restrict__ Wco, const u16* __restrict__ wo_bf,
    const u16* __restrict__ qT, const u16* __restrict__ xT,
    const float* __restrict__ bo, float* __restrict__ out)
{
    const int bid = blockIdx.x;                   // 4800 blocks
    const int swz = (bid & 7) * 600 + (bid >> 3); // T1 chunked (4800%8==0)
    const int m_t = swz & 3;
    const int tmp = swz >> 2;
    const int n_t = tmp % 150;
    const int b   = tmp / 150;
    const int m0 = m_t * 128, n0 = n_t * 96;
    const int t = threadIdx.x, lane = t & 63, w = t >> 6;
    const int wm = w >> 1, wn = w & 1;

    __shared__ __align__(16) u16 As[128 * 64];
    __shared__ __align__(16) u16 Bs[96 * 64];

    const int srow = lane >> 3;
    const int kus  = (lane & 7) * 8;

    f32x4 acc[4][3];
    #pragma unroll
    for (int i = 0; i < 4; ++i)
        #pragma unroll
        for (int j = 0; j < 3; ++j)
            acc[i][j] = (f32x4){0.f, 0.f, 0.f, 0.f};

    for (int k0 = 0; k0 < 576; k0 += 64) {
        bf16x8 ar[4], br[3];
        if (k0 == 0) {
            #pragma unroll
            for (int i = 0; i < 4; ++i) {
                int row = (w * 4 + i) * 8 + srow;
                ar[i] = *(const bf16x8*)(Wco + (size_t)(m0 + row) * 512 + b * 64 + kus);
            }
            #pragma unroll
            for (int i = 0; i < 3; ++i) {
                int row = (w * 3 + i) * 8 + srow;
                br[i] = *(const bf16x8*)(qT + ((size_t)b * NSP + n0 + row) * 64 + kus);
            }
        } else {
            const int kc = k0 - 64;
            #pragma unroll
            for (int i = 0; i < 4; ++i) {
                int row = (w * 4 + i) * 8 + srow;
                ar[i] = *(const bf16x8*)(wo_bf + (size_t)(m0 + row) * 512 + kc + kus);
            }
            #pragma unroll
            for (int i = 0; i < 3; ++i) {
                int row = (w * 3 + i) * 8 + srow;
                br[i] = *(const bf16x8*)(xT + ((size_t)b * NSP + n0 + row) * 512 + kc + kus);
            }
        }
        __syncthreads();
        #pragma unroll
        for (int i = 0; i < 4; ++i) {
            int row = (w * 4 + i) * 8 + srow;
            *(bf16x8*)&As[row * 64 + (kus ^ ((row & 7) << 3))] = ar[i];
        }
        #pragma unroll
        for (int i = 0; i < 3; ++i) {
            int row = (w * 3 + i) * 8 + srow;
            *(bf16x8*)&Bs[row * 64 + (kus ^ ((row & 7) << 3))] = br[i];
        }
        __syncthreads();
        #pragma unroll
        for (int kk = 0; kk < 2; ++kk) {
            const int kf = kk * 32 + (lane >> 4) * 8;
            bf16x8 af[4], bg[3];
            #pragma unroll
            for (int fm = 0; fm < 4; ++fm) {
                int ml = wm * 64 + fm * 16 + (lane & 15);
                af[fm] = *(const bf16x8*)&As[ml * 64 + (kf ^ ((ml & 7) << 3))];
            }
            #pragma unroll
            for (int fn = 0; fn < 3; ++fn) {
                int nl = wn * 48 + fn * 16 + (lane & 15);
                bg[fn] = *(const bf16x8*)&Bs[nl * 64 + (kf ^ ((nl & 7) << 3))];
            }
            #pragma unroll
            for (int fm = 0; fm < 4; ++fm)
                #pragma unroll
                for (int fn = 0; fn < 3; ++fn)
                    acc[fm][fn] = __builtin_amdgcn_mfma_f32_16x16x32_bf16(
                        af[fm], bg[fn], acc[fm][fn], 0, 0, 0);
        }
    }

    const int rbase = (lane >> 4) * 4;
    const int cloc  = lane & 15;
    #pragma unroll
    for (int fm = 0; fm < 4; ++fm) {
        #pragma unroll
        for (int fn = 0; fn < 3; ++fn) {
            const int gm = m0 + wm * 64 + fm * 16 + rbase;
            const int gn = n0 + wn * 48 + fn * 16 + cloc;
            #pragma unroll
            for (int r = 0; r < 4; ++r)
                out[((size_t)b * 512 + gm + r) * NSP + gn] = acc[fm][fn][r] + bo[gm + r];
        }
    }
}

// ---------------- launcher ----------------
extern "C" void kernel_launch(void* const* d_in, const int* in_sizes, int n_in,
                              void* d_out, int out_size, void* d_ws, size_t ws_size,
                              hipStream_t stream)
{
    const float* x     = (const float*)d_in[0];
    const float* Wq    = (const float*)d_in[1];
    const float* bq    = (const float*)d_in[2];
    const float* Wk    = (const float*)d_in[3];
    const float* bk    = (const float*)d_in[4];
    const float* Wv    = (const float*)d_in[5];
    const float* bv    = (const float*)d_in[6];
    const float* gamma = (const float*)d_in[7];
    const float* Wo    = (const float*)d_in[8];
    const float* bo    = (const float*)d_in[9];
    float* out = (float*)d_out;

    // ---- workspace carve (bytes, 256-aligned) ----
    char* base = (char*)d_ws;
    size_t off = 0;
    auto carve = [&](size_t bytes) { char* p = base + off; off = (off + bytes + 255) & ~(size_t)255; return p; };
    u16*   wqk   = (u16*)  carve(128 * 512 * 2);
    u16*   wo_bf = (u16*)  carve(512 * 512 * 2);
    float* bqk   = (float*)carve(128 * 4);
    float* Wov   = (float*)carve(512 * 512 * 4);
    float* bovp  = (float*)carve(512 * 4);
    u16*   xT    = (u16*)  carve((size_t)BSZ * NSP * CCH * 2);      // 118 MB
    u16*   xbf   = (u16*)  carve((size_t)BSZ * CCH * NSP * 2);      // 118 MB
    float* Okk   = (float*)carve((size_t)BSZ * 64 * NSP * 4);       //  29.5 MB
    float* kmax  = (float*)carve(512 * 4);
    float* kinv  = (float*)carve(512 * 4);
    u16*   qT    = (u16*)  carve((size_t)BSZ * NSP * 64 * 2);       //  14.7 MB
    float* part  = (float*)carve((size_t)25 * BSZ * 64 * 512 * 4);  //  26.2 MB
    float* KXf   = (float*)carve((size_t)BSZ * 64 * 512 * 4);       //   1 MB
    u16*   Wco   = (u16*)  carve(512 * 512 * 2);

    // 1. weight prep
    prep_w<<<dim3((128 * 512 + 512 * 512 + 128 + 255) / 256), dim3(256), 0, stream>>>(
        Wq, Wk, Wo, bq, bk, wqk, wo_bf, bqk);
    // 2. Wov = Wo @ Wv ; bov = Wo @ bv
    wov_gemm<<<dim3(8, 8), dim3(256), 0, stream>>>(Wo, Wv, Wov);
    bov_kernel<<<dim3(8), dim3(64), 0, stream>>>(Wo, bv, bovp);
    // 3. x -> xT bf16 [b][n][c]  +  xbf bf16 [b][c][n]
    xpose_cvt<<<dim3(NSP / 64, CCH / 64, BSZ), dim3(256), 0, stream>>>(x, xT, xbf);
    // 4. qk GEMM with fused q-softmax; k rows -> Okk f32
    qk_gemm<<<dim3(NSP / 96, 1, BSZ), dim3(256), 0, stream>>>(wqk, xT, bqk, Okk, qT);
    // 5. k softmax stats
    k_stats<<<dim3(BSZ * 64), dim3(256), 0, stream>>>(Okk, kmax, kinv);
    // 6. KX = ksm @ x^T via MFMA (split-25), then reduce
    kx_mfma<<<dim3(4 * 25 * BSZ), dim3(256), 0, stream>>>(Okk, xbf, kmax, kinv, part);
    kx_reduce<<<dim3(262144 / 256), dim3(256), 0, stream>>>(part, KXf);
    // 7. Wco = gamma*(Wov @ KX^T + bov) bf16
    wco_gemm<<<dim3(8, 8), dim3(256), 0, stream>>>(Wov, KXf, bovp, gamma, Wco);
    // 8. fused output GEMM (K = 64 qT + 512 xT)
    fused_out<<<dim3(4 * 150 * BSZ), dim3(256), 0, stream>>>(Wco, wo_bf, qT, xT, bo, out);
}